// Round 2
// 231.956 us; speedup vs baseline: 1.0099x; 1.0099x over previous
//
#include <hip/hip_runtime.h>
#include <math.h>

#define BB   2
#define CFI  32
#define NN   36864          // 192*192
#define NUMM 16

// workspace: Y at ws[0..], Z at ws[ZOFS..]  (point-major [B*N][32] each)
#define ZOFS (BB * NN * CFI)

typedef __attribute__((ext_vector_type(8))) short short8;   // 8 bf16 (4 VGPRs)
typedef __attribute__((ext_vector_type(4))) float f4;       // 4 f32
typedef __attribute__((ext_vector_type(16))) float f16v;    // 16 f32 (32x32 acc)

static __device__ __forceinline__ f16v mm32(short8 a, short8 b, f16v c) {
    return __builtin_amdgcn_mfma_f32_32x32x16_bf16(a, b, c, 0, 0, 0);
}

// tanh-form gelu: x * sigmoid(1.595769x + 0.0713548x^3), exp2-folded.
static __device__ __forceinline__ float gelu_fast(float x) {
    const float x2  = x * x;
    const float q   = fmaf(-0.10294310f, x2, -2.30211813f);
    const float e   = exp2f(q * x);
    const float r   = __builtin_amdgcn_rcpf(e + 1.0f);
    return x * r;
}

static __device__ __forceinline__ unsigned bf16_rne_bits(float x) {
    unsigned u = __builtin_bit_cast(unsigned, x);
    return u + 0x7fffu + ((u >> 16) & 1u);
}
static __device__ __forceinline__ void split_pack(float x0, float x1,
                                                  unsigned& hi, unsigned& lo) {
    unsigned r0 = bf16_rne_bits(x0);
    unsigned r1 = bf16_rne_bits(x1);
    float h0 = __builtin_bit_cast(float, r0 & 0xffff0000u);
    float h1 = __builtin_bit_cast(float, r1 & 0xffff0000u);
    hi = (r0 >> 16) | (r1 & 0xffff0000u);
    unsigned s0 = bf16_rne_bits(x0 - h0);
    unsigned s1 = bf16_rne_bits(x1 - h1);
    lo = (s0 >> 16) | (s1 & 0xffff0000u);
}

// cheap round-half-up bf16 pair pack (activations)
static __device__ __forceinline__ unsigned pack2(float a, float b) {
    unsigned ua = __builtin_bit_cast(unsigned, a) + 0x8000u;
    unsigned ub = __builtin_bit_cast(unsigned, b) + 0x8000u;
    return (ua >> 16) | (ub & 0xffff0000u);
}

union UV { unsigned u[4]; short8 v; };

// ---- kernel A: per-point Y/Z precompute (layer-1 split) -- unchanged ------
__global__ __launch_bounds__(256) void yz_kernel(
    const float* __restrict__ If, const float* __restrict__ Pf,
    const float* __restrict__ W1, const float* __restrict__ g1,
    const float* __restrict__ b1, const float* __restrict__ m1,
    const float* __restrict__ v1,
    float* __restrict__ wsYZ)
{
    __shared__ float wy[1024], wz[1024], wp[32], bt1[32];
    for (int i = threadIdx.x; i < 1024; i += 256) {
        int o = i >> 5, c = i & 31;
        float inv = g1[o] * rsqrtf(v1[o] + 1e-5f);
        wy[i] = W1[o * 67 + c]      * inv;
        wz[i] = W1[o * 67 + 32 + c] * inv;
    }
    if (threadIdx.x < 32) {
        int o = threadIdx.x;
        float inv = g1[o] * rsqrtf(v1[o] + 1e-5f);
        wp[o]  = W1[o * 67 + 64] * inv;
        bt1[o] = b1[o] - m1[o] * inv;
    }
    __syncthreads();

    const int r  = threadIdx.x & 3;
    const int p  = blockIdx.x * 64 + (threadIdx.x >> 2);
    const int b  = p / NN, n = p - b * NN;
    const int o0 = r * 8;
    const float* ifp = If + (size_t)b * CFI * NN + n;

    float v[32];
#pragma unroll
    for (int c = 0; c < 32; c++) v[c] = ifp[(size_t)c * NN];
    const float pf = Pf[p];

    float accY[8], accZ[8];
#pragma unroll
    for (int j = 0; j < 8; j++) {
        const float4* wyr = (const float4*)&wy[(o0 + j) * 32];
        const float4* wzr = (const float4*)&wz[(o0 + j) * 32];
        float ay = bt1[o0 + j];
        float az = wp[o0 + j] * pf;
#pragma unroll
        for (int c4 = 0; c4 < 8; c4++) {
            float4 a = wyr[c4], z = wzr[c4];
            ay = fmaf(a.x, v[4 * c4 + 0], ay);  az = fmaf(z.x, v[4 * c4 + 0], az);
            ay = fmaf(a.y, v[4 * c4 + 1], ay);  az = fmaf(z.y, v[4 * c4 + 1], az);
            ay = fmaf(a.z, v[4 * c4 + 2], ay);  az = fmaf(z.z, v[4 * c4 + 2], az);
            ay = fmaf(a.w, v[4 * c4 + 3], ay);  az = fmaf(z.w, v[4 * c4 + 3], az);
        }
        accY[j] = ay; accZ[j] = az;
    }

    float4* yp = (float4*)(wsYZ + (size_t)p * 32 + o0);
    float4* zp = (float4*)(wsYZ + ZOFS + (size_t)p * 32 + o0);
    yp[0] = make_float4(accY[0], accY[1], accY[2], accY[3]);
    yp[1] = make_float4(accY[4], accY[5], accY[6], accY[7]);
    zp[0] = make_float4(accZ[0], accZ[1], accZ[2], accZ[3]);
    zp[1] = make_float4(accZ[4], accZ[5], accZ[6], accZ[7]);
}

// ---- kernel B: 32x32x16 MFMA MLP, 2 points per wave-pass ------------------
// r15: the MFMA pairs A-elem (g,j) with B-elem (g,j), so any bijective
// (g,j)->k map works if A-init and B-build share it. Choose
// phi(g,j) = 4g + (j&3) + 8*(j>>2) == the C-layout rows that lane (col,g)
// already holds. Inter-layer relayout = 8 pack2, ZERO cross-lane ops.
// C layout (HW-verified): col=lane&31, row=(reg&3)+8*(reg>>2)+4*(lane>>5).
#define LAYER(Lc, BIN0, BIN1, ACCV)                                           \
    {                                                                         \
        const f4 bq0 = *(const f4*)&btl[(Lc) * 32 +      4 * hi + 4 * io];    \
        const f4 bq1 = *(const f4*)&btl[(Lc) * 32 +  8 + 4 * hi + 4 * io];    \
        const f4 bq2 = *(const f4*)&btl[(Lc) * 32 + 16 + 4 * hi + 4 * io];    \
        const f4 bq3 = *(const f4*)&btl[(Lc) * 32 + 24 + 4 * hi + 4 * io];    \
        ACCV[0]  = bq0[0]; ACCV[1]  = bq0[1]; ACCV[2]  = bq0[2]; ACCV[3]  = bq0[3]; \
        ACCV[4]  = bq1[0]; ACCV[5]  = bq1[1]; ACCV[6]  = bq1[2]; ACCV[7]  = bq1[3]; \
        ACCV[8]  = bq2[0]; ACCV[9]  = bq2[1]; ACCV[10] = bq2[2]; ACCV[11] = bq2[3]; \
        ACCV[12] = bq3[0]; ACCV[13] = bq3[1]; ACCV[14] = bq3[2]; ACCV[15] = bq3[3]; \
        short8 Af;                                                            \
        Af = *(const short8*)&wfrag[(Lc)][0][1][lane + io][0];                \
        ACCV = mm32(Af, BIN0.v, ACCV);                                        \
        Af = *(const short8*)&wfrag[(Lc)][0][0][lane + io][0];                \
        ACCV = mm32(Af, BIN0.v, ACCV);                                        \
        Af = *(const short8*)&wfrag[(Lc)][1][1][lane + io][0];                \
        ACCV = mm32(Af, BIN1.v, ACCV);                                        \
        Af = *(const short8*)&wfrag[(Lc)][1][0][lane + io][0];                \
        ACCV = mm32(Af, BIN1.v, ACCV);                                        \
    }

// C regs (gelu'd, register order == phi order) -> next-layer B fragments.
#define RELAYOUT(SRC, B0V, B1V)                                               \
    {                                                                         \
        B0V.u[0] = pack2(SRC[0],  SRC[1]);                                    \
        B0V.u[1] = pack2(SRC[2],  SRC[3]);                                    \
        B0V.u[2] = pack2(SRC[4],  SRC[5]);                                    \
        B0V.u[3] = pack2(SRC[6],  SRC[7]);                                    \
        B1V.u[0] = pack2(SRC[8],  SRC[9]);                                    \
        B1V.u[1] = pack2(SRC[10], SRC[11]);                                   \
        B1V.u[2] = pack2(SRC[12], SRC[13]);                                   \
        B1V.u[3] = pack2(SRC[14], SRC[15]);                                   \
    }

__global__ __launch_bounds__(256, 5) void main_kernel(
    const float* __restrict__ Pf, const float* __restrict__ Of,
    const int* __restrict__ args,
    const float* __restrict__ W1, const float* __restrict__ g1,
    const float* __restrict__ v1,
    const float* __restrict__ W2, const float* __restrict__ g2,
    const float* __restrict__ b2, const float* __restrict__ m2,
    const float* __restrict__ v2,
    const float* __restrict__ W3, const float* __restrict__ g3,
    const float* __restrict__ b3, const float* __restrict__ m3,
    const float* __restrict__ v3,
    const float* __restrict__ W4, const float* __restrict__ g4,
    const float* __restrict__ b4, const float* __restrict__ m4,
    const float* __restrict__ v4,
    const float* __restrict__ Wc, const float* __restrict__ bc,
    const float* __restrict__ ws, float* __restrict__ out)
{
    __shared__ __align__(16) unsigned wfrag[3][2][2][64][4]; // L,khalf,hi/lo,lane,pair
    __shared__ __align__(16) float btl[3 * 32];   // BN beta by [L][ch]
    __shared__ __align__(16) float wch[3 * 32];   // Wc rows A,B,O by ch
    __shared__ __align__(16) float w1t[2 * 32];   // W1 cols 65,66 folded, by ch
    __shared__ float bcs[3];
    __shared__ int   izs;

    const float* Ws[3] = {W2, W3, W4};
    const float* gs[3] = {g2, g3, g4};
    const float* vs[3] = {v2, v3, v4};
    const float* bs[3] = {b2, b3, b4};
    const float* ms[3] = {m2, m3, m4};

    for (int idx = threadIdx.x; idx < 1536; idx += 256) {
        int pp  = idx & 3;
        int ln  = (idx >> 2) & 63;
        int kh  = (idx >> 8) & 1;
        int L   = idx >> 9;
        int row = ln & 31;
        int g   = ln >> 5;
        // phi(g, e) = 4g + (e&3) + 8*(e>>2); pair pp covers elems 2pp, 2pp+1
        int k   = kh * 16 + 4 * g + 2 * (pp & 1) + 8 * (pp >> 1);
        float inv = gs[L][row] * rsqrtf(vs[L][row] + 1e-5f);
        float w0 = Ws[L][row * 32 + k]     * inv;
        float w1 = Ws[L][row * 32 + k + 1] * inv;
        unsigned hiw, low;
        split_pack(w0, w1, hiw, low);
        wfrag[L][kh][0][ln][pp] = hiw;
        wfrag[L][kh][1][ln][pp] = low;
    }
    if (threadIdx.x < 96) {
        int L = threadIdx.x >> 5, ch = threadIdx.x & 31;
        btl[threadIdx.x] = bs[L][ch] - ms[L][ch] * (gs[L][ch] * rsqrtf(vs[L][ch] + 1e-5f));
        wch[threadIdx.x] = Wc[L * 32 + ch];
    }
    if (threadIdx.x < 64) {
        int t = threadIdx.x >> 5, ch = threadIdx.x & 31;
        float i1 = g1[ch] * rsqrtf(v1[ch] + 1e-5f);
        w1t[threadIdx.x] = W1[ch * 67 + 65 + t] * i1;
    }
    if (threadIdx.x < 3) bcs[threadIdx.x] = bc[threadIdx.x];
    if (threadIdx.x == 0) izs = (int)(args[0] >> 16);   // == 0, opaque
    __syncthreads();

    const int lane  = threadIdx.x & 63;
    const int wid   = threadIdx.x >> 6;
    const int m     = lane & 15;          // m-index (softmax axis)
    const int pt    = (lane >> 4) & 1;    // which of the 2 points in the pass
    const int hi    = lane >> 5;          // k-group
    const int q4    = hi << 2;            // 4*hi
    const int izero = izs;                // 0, compiler-opaque

#pragma unroll 1
    for (int i = 0; i < 2; i++) {
        const int io = i & izero;                         // 0 every iter, unprovable
        const int C  = blockIdx.x * 16 + wid * 4 + i * 2 + pt;
        const int b  = (C >= NN) ? 1 : 0;
        const int n  = C - b * NN;

        const int   aIdx = args[(b * NUMM + m) * NN + n];
        const float of0v = Of[((b * 2 + 0) * NUMM + m) * NN + n];
        const float of1v = Of[((b * 2 + 1) * NUMM + m) * NN + n];
        const float pfg  = Pf[b * NN + aIdx];

        // this lane supplies channels {4hi..4hi+3, 8+4hi.., 16+4hi.., 24+4hi..}
        const f4* yb = (const f4*)(ws + (size_t)(b * NN + n) * 32);
        const f4* zb = (const f4*)(ws + ZOFS + (size_t)(b * NN + aIdx) * 32);
        f4 y0 = yb[hi], y1 = yb[2 + hi], y2 = yb[4 + hi], y3 = yb[6 + hi];
        f4 z0 = zb[hi], z1 = zb[2 + hi], z2 = zb[4 + hi], z3 = zb[6 + hi];

        const f4 wa0 = *(const f4*)&w1t[q4 + 4 * io];
        const f4 wa1 = *(const f4*)&w1t[8 + q4 + 4 * io];
        const f4 wa2 = *(const f4*)&w1t[16 + q4 + 4 * io];
        const f4 wa3 = *(const f4*)&w1t[24 + q4 + 4 * io];
        const f4 wb0 = *(const f4*)&w1t[32 + q4 + 4 * io];
        const f4 wb1 = *(const f4*)&w1t[40 + q4 + 4 * io];
        const f4 wb2 = *(const f4*)&w1t[48 + q4 + 4 * io];
        const f4 wb3 = *(const f4*)&w1t[56 + q4 + 4 * io];

        // ---- layer 1: h1 = gelu(Y+Z+of terms) -> directly the B fragments ----
        float x[16];
#pragma unroll
        for (int j = 0; j < 4; j++) {
            x[j]      = fmaf(of1v, wb0[j], fmaf(of0v, wa0[j], y0[j] + z0[j]));
            x[4 + j]  = fmaf(of1v, wb1[j], fmaf(of0v, wa1[j], y1[j] + z1[j]));
            x[8 + j]  = fmaf(of1v, wb2[j], fmaf(of0v, wa2[j], y2[j] + z2[j]));
            x[12 + j] = fmaf(of1v, wb3[j], fmaf(of0v, wa3[j], y3[j] + z3[j]));
        }
#pragma unroll
        for (int j = 0; j < 16; j++) x[j] = gelu_fast(x[j]);
        UV B0, B1;
        RELAYOUT(x, B0, B1);

        // ---- layer 2 ----
        f16v acc;
        LAYER(0, B0, B1, acc);
        float h2g[16];
#pragma unroll
        for (int r = 0; r < 16; r++) h2g[r] = gelu_fast(acc[r]);
        RELAYOUT(h2g, B0, B1);

        // ---- layer 3 ----
        LAYER(1, B0, B1, acc);
        float h3g[16];
#pragma unroll
        for (int r = 0; r < 16; r++) h3g[r] = gelu_fast(acc[r]);
        RELAYOUT(h3g, B0, B1);

        // ---- layer 4 + residual + head (all in C layout) ----
        LAYER(2, B0, B1, acc);

        float pa = 0.0f, pb = 0.0f, po = 0.0f;
#pragma unroll
        for (int q = 0; q < 4; q++) {
            const f4 wAq = *(const f4*)&wch[      8 * q + q4 + 4 * io];
            const f4 wBq = *(const f4*)&wch[32 +  8 * q + q4 + 4 * io];
            const f4 wOq = *(const f4*)&wch[64 +  8 * q + q4 + 4 * io];
#pragma unroll
            for (int r2 = 0; r2 < 4; r2++) {
                float xf = gelu_fast(h2g[4 * q + r2] + acc[4 * q + r2]);
                pa = fmaf(wAq[r2], xf, pa);
                pb = fmaf(wBq[r2], xf, pb);
                po = fmaf(wOq[r2], xf, po);
            }
        }
        // partner half (lane^32) holds the other 16 channels
        pa += __shfl_xor(pa, 32, 64);
        pb += __shfl_xor(pb, 32, 64);
        po += __shfl_xor(po, 32, 64);

        const float alpha = pa + bcs[0];
        const float beta_ = pb + bcs[1];
        const float omega = po + bcs[2];
        const float val = fmaf(alpha + 1.0f, pfg, beta_);

        // softmax over the 16 m's (within each 16-lane group)
        float mx = omega;
#pragma unroll
        for (int s = 1; s < 16; s <<= 1) mx = fmaxf(mx, __shfl_xor(mx, s, 64));
        const float e = __expf(omega - mx);
        float S = e, T = val * e;
#pragma unroll
        for (int s = 1; s < 16; s <<= 1) {
            S += __shfl_xor(S, s, 64);
            T += __shfl_xor(T, s, 64);
        }
        if ((lane & 15) == 0 && lane < 32)
            out[b * NN + n] = T * __builtin_amdgcn_rcpf(S);
    }
}

// ---- launcher ---------------------------------------------------------------
extern "C" void kernel_launch(void* const* d_in, const int* in_sizes, int n_in,
                              void* d_out, int out_size, void* d_ws, size_t ws_size,
                              hipStream_t stream) {
    const float* If    = (const float*)d_in[0];
    const float* Pf    = (const float*)d_in[1];
    const float* Of    = (const float*)d_in[2];
    const int*   args  = (const int*)d_in[3];
    const float* W1    = (const float*)d_in[4];
    const float* g1    = (const float*)d_in[5];
    const float* b1    = (const float*)d_in[6];
    const float* m1    = (const float*)d_in[7];
    const float* v1    = (const float*)d_in[8];
    const float* W2    = (const float*)d_in[9];
    const float* g2    = (const float*)d_in[10];
    const float* b2    = (const float*)d_in[11];
    const float* m2    = (const float*)d_in[12];
    const float* v2    = (const float*)d_in[13];
    const float* W3    = (const float*)d_in[14];
    const float* g3    = (const float*)d_in[15];
    const float* b3    = (const float*)d_in[16];
    const float* m3    = (const float*)d_in[17];
    const float* v3    = (const float*)d_in[18];
    const float* W4    = (const float*)d_in[19];
    const float* g4    = (const float*)d_in[20];
    const float* b4    = (const float*)d_in[21];
    const float* m4    = (const float*)d_in[22];
    const float* v4    = (const float*)d_in[23];
    const float* Wc    = (const float*)d_in[24];
    const float* bc    = (const float*)d_in[25];

    float* ws  = (float*)d_ws;
    float* out = (float*)d_out;

    yz_kernel<<<(BB * NN) / 64, 256, 0, stream>>>(
        If, Pf, W1, g1, b1, m1, v1, ws);

    main_kernel<<<(BB * NN) / 16, 256, 0, stream>>>(
        Pf, Of, args,
        W1, g1, v1,
        W2, g2, b2, m2, v2,
        W3, g3, b3, m3, v3,
        W4, g4, b4, m4, v4,
        Wc, bc, ws, out);
}